// Round 15
// baseline (303.650 us; speedup 1.0000x reference)
//
#include <hip/hip_runtime.h>
#include <math.h>

#define B_  256
#define H_  200
#define N_  64
#define D_  640
#define DT_ 256
#define NH_ 10
#define HD_ 64
#define MT_ 13   // 13 m-tiles of 16 cover 208 >= 200
#define MH_ 25600  // M half (B_*H_/2)

typedef __attribute__((ext_vector_type(8))) short bf16x8;
typedef __attribute__((ext_vector_type(4))) float f32x4;

__device__ __forceinline__ float wave_reduce_sum(float v) {
    #pragma unroll
    for (int m = 32; m > 0; m >>= 1) v += __shfl_xor(v, m);
    return v;
}
__device__ __forceinline__ float wave_reduce_max(float v) {
    #pragma unroll
    for (int m = 32; m > 0; m >>= 1) v = fmaxf(v, __shfl_xor(v, m));
    return v;
}
__device__ __forceinline__ float red16_sum(float v) {   // reduce over lane&15 group
    #pragma unroll
    for (int m = 1; m < 16; m <<= 1) v += __shfl_xor(v, m);
    return v;
}
__device__ __forceinline__ float red16_max(float v) {
    #pragma unroll
    for (int m = 1; m < 16; m <<= 1) v = fmaxf(v, __shfl_xor(v, m));
    return v;
}
__device__ __forceinline__ short f2bf(float x) {   // RNE bf16
    unsigned u = __float_as_uint(x);
    unsigned r = (u + 0x7fffu + ((u >> 16) & 1u)) >> 16;
    return (short)r;
}
__device__ __forceinline__ float bf2f(short s) {
    return __uint_as_float(((unsigned)(unsigned short)s) << 16);
}

__device__ __forceinline__ void gload_lds16(const void* g, void* lds) {
    __builtin_amdgcn_global_load_lds(
        (const __attribute__((address_space(1))) void*)g,
        (__attribute__((address_space(3))) void*)lds, 16, 0, 0);
}

__global__ __launch_bounds__(256) void convert_w(
    const float* __restrict__ src, short* __restrict__ dst, int n)
{
    for (int i = blockIdx.x * 256 + threadIdx.x; i < n; i += gridDim.x * 256)
        dst[i] = f2bf(src[i]);
}

// gemm_bt v2: Y_bf16[row,col] = bf16( sum_k A[row,k]*W[col,k] (+ bias[col]) ).
// BM=128, BN=128, BK=32, 256 threads = 4 waves (2x2), acc[4][4].
// T3-minimum 2-phase pipeline: BOTH operands double-buffered (48 KB total,
// 3 blocks/CU); STAGE(k+1) issued BEFORE compute(k); ONE barrier per chunk.
// The end-of-chunk barrier (vmcnt(0) drain) lands k+1's loads, which have
// had the whole compute phase (x3 resident blocks) to complete.
// Rule-21 both-sides swizzle on A (XOR row&7) and B (XOR (col>>1)&3).
// Bijective XCD remap (grid % 8 == 0) keeps an A-panel's 5 col-strips on
// one XCD (panel + W reused from its L2).
__global__ __launch_bounds__(256, 3) void gemm_bt(
    const float* __restrict__ A, int lda,
    const short* __restrict__ Wb, int ldb,
    const float* __restrict__ bias,
    short* __restrict__ Y, int nkc)
{
    __shared__ float A_f[2][128 * 32];   // 2 x 16 KB fp32, slot-swizzled
    __shared__ short B_l[2][128 * 32];   // 2 x  8 KB bf16, slot-swizzled
    const int t = threadIdx.x;
    const int lane = t & 63, w = t >> 6;
    const int wm = w >> 1, wn = w & 1;
    const int r16 = lane & 15, g = lane >> 4;
    const int lb = (blockIdx.x & 7) * ((int)gridDim.x >> 3) + (blockIdx.x >> 3);
    const int row0 = (lb / 5) * 128;
    const int col0 = (lb % 5) * 128;

    f32x4 acc[4][4];
    #pragma unroll
    for (int ct = 0; ct < 4; ++ct)
        #pragma unroll
        for (int rt = 0; rt < 4; ++rt) acc[ct][rt] = (f32x4){0.f,0.f,0.f,0.f};

    // stage chunk k into buffer bi (6 gload_lds16 per thread)
    auto STAGE = [&](int bi, int k) {
        const int k0 = k * 32;
        // A: 1024 granules (16B = 4 floats), 4/thread
        #pragma unroll
        for (int j = 0; j < 4; ++j) {
            const int u = t + j * 256;
            const int row = u >> 3, jj = u & 7;
            gload_lds16(A + (long)(row0 + row) * lda + k0 + ((jj ^ (row & 7)) << 2),
                        (char*)A_f[bi] + u * 16);
        }
        // B: 512 granules (16B = 8 bf16), 2/thread
        #pragma unroll
        for (int j = 0; j < 2; ++j) {
            const int u = t + j * 256;
            const int col = u >> 2, jj = u & 3;
            gload_lds16(Wb + (long)(col0 + col) * ldb + k0 + ((jj ^ ((col >> 1) & 3)) << 3),
                        (char*)B_l[bi] + u * 16);
        }
    };

    STAGE(0, 0);
    __syncthreads();

    for (int k = 0; k < nkc; ++k) {
        if (k + 1 < nkc) STAGE((k + 1) & 1, k + 1);   // issue BEFORE compute

        const float* ab = A_f[k & 1];
        const short* bb = B_l[k & 1];
        bf16x8 a[4];
        #pragma unroll
        for (int rt = 0; rt < 4; ++rt) {
            const int row = wm * 64 + rt * 16 + r16;
            const int s0 = (g * 2) ^ (row & 7);
            const int s1 = (g * 2 + 1) ^ (row & 7);
            float4 f0 = *(const float4*)(ab + row * 32 + s0 * 4);
            float4 f1 = *(const float4*)(ab + row * 32 + s1 * 4);
            bf16x8 av;
            av[0] = f2bf(f0.x); av[1] = f2bf(f0.y); av[2] = f2bf(f0.z); av[3] = f2bf(f0.w);
            av[4] = f2bf(f1.x); av[5] = f2bf(f1.y); av[6] = f2bf(f1.z); av[7] = f2bf(f1.w);
            a[rt] = av;
        }
        bf16x8 b[4];
        #pragma unroll
        for (int ct = 0; ct < 4; ++ct) {
            const int col = wn * 64 + ct * 16 + r16;
            const int sb = g ^ ((col >> 1) & 3);
            b[ct] = *(const bf16x8*)(bb + col * 32 + sb * 8);
        }
        #pragma unroll
        for (int ct = 0; ct < 4; ++ct)
            #pragma unroll
            for (int rt = 0; rt < 4; ++rt)
                acc[ct][rt] = __builtin_amdgcn_mfma_f32_16x16x32_bf16(
                                  a[rt], b[ct], acc[ct][rt], 0, 0, 0);
        __syncthreads();   // lands k+1's loads; frees buf[k&1] for k+2's STAGE
    }

    // write Y bf16: C/D layout col = lane&15, row = g*4 + i
    #pragma unroll
    for (int ct = 0; ct < 4; ++ct) {
        const int col = col0 + wn * 64 + ct * 16 + r16;
        const float bv = bias ? bias[col] : 0.f;
        #pragma unroll
        for (int rt = 0; rt < 4; ++rt)
            #pragma unroll
            for (int i = 0; i < 4; ++i)
                Y[(long)(row0 + wm * 64 + rt * 16 + g * 4 + i) * D_ + col] =
                    f2bf(acc[ct][rt][i] + bv);
    }
}

// Fused attention + aggregation, one batch b per block.
__global__ __launch_bounds__(512, 2) void attn2(
    const short* __restrict__ Qb, const short* __restrict__ Kb,
    float* __restrict__ aw, float* __restrict__ out_tail)
{
    __shared__ float qn_l[N_];
    __shared__ float qw_l[N_];
    __shared__ float aggp[8][MT_ * 16];
    __shared__ float red2[2];
    const int t = threadIdx.x;
    const int lane = t & 63, w = t >> 6;
    const int wm = w & 3, hh = w >> 2;
    const int r16 = lane & 15, g = lane >> 4;
    const int b = blockIdx.x;

    if (hh == 0) {
        const short* qrow = Qb + ((long)(b * N_ + wm * 16 + r16)) * D_ + g * 160;
        float ss = 0.f;
        #pragma unroll
        for (int j = 0; j < 20; ++j) {
            bf16x8 v = *(const bf16x8*)(qrow + j * 8);
            #pragma unroll
            for (int e = 0; e < 8; ++e) { float f = bf2f(v[e]); ss += f * f; }
        }
        ss += __shfl_xor(ss, 16);
        ss += __shfl_xor(ss, 32);
        if (g == 0) qn_l[wm * 16 + r16] = ss;
    }
    __syncthreads();
    if (w == 0) {
        float v = sqrtf(qn_l[lane]);
        float mx = wave_reduce_max(v);
        float e = __expf(v - mx);
        float s = wave_reduce_sum(e);
        qw_l[lane] = e / s;
    }
    __syncthreads();

    float qwr[4];
    #pragma unroll
    for (int i = 0; i < 4; ++i) qwr[i] = qw_l[wm * 16 + g * 4 + i];

    const float inv_scale = 0.0395284707521047f;   // 1/sqrt(640)
    float aggl[MT_];
    #pragma unroll
    for (int mt = 0; mt < MT_; ++mt) aggl[mt] = 0.f;

    for (int hi = 0; hi < 5; ++hi) {
        const int h = hh * 5 + hi;
        const short* qbase = Qb + ((long)(b * N_ + wm * 16 + r16)) * D_ + h * HD_ + g * 8;
        bf16x8 a0 = *(const bf16x8*)(qbase);
        bf16x8 a1 = *(const bf16x8*)(qbase + 32);
        bf16x8 kb0[MT_], kb1[MT_];
        #pragma unroll
        for (int mt = 0; mt < MT_; ++mt) {
            const short* kbase = Kb + ((long)(b * H_ + mt * 16 + r16)) * D_ + h * HD_ + g * 8;
            kb0[mt] = *(const bf16x8*)(kbase);
            kb1[mt] = *(const bf16x8*)(kbase + 32);
        }
        f32x4 acc[MT_];
        #pragma unroll
        for (int mt = 0; mt < MT_; ++mt) {
            f32x4 z = {0.f,0.f,0.f,0.f};
            z = __builtin_amdgcn_mfma_f32_16x16x32_bf16(a0, kb0[mt], z, 0, 0, 0);
            z = __builtin_amdgcn_mfma_f32_16x16x32_bf16(a1, kb1[mt], z, 0, 0, 0);
            acc[mt] = z;
        }
        const bool tailok = (r16 < 8);
        float mx[4] = {-INFINITY, -INFINITY, -INFINITY, -INFINITY};
        #pragma unroll
        for (int mt = 0; mt < MT_; ++mt) {
            const bool valid = (mt < 12) || tailok;
            #pragma unroll
            for (int i = 0; i < 4; ++i)
                if (valid) mx[i] = fmaxf(mx[i], acc[mt][i]);
        }
        #pragma unroll
        for (int i = 0; i < 4; ++i) mx[i] = red16_max(mx[i]);
        float sum[4] = {0.f, 0.f, 0.f, 0.f};
        #pragma unroll
        for (int mt = 0; mt < MT_; ++mt) {
            const bool valid = (mt < 12) || tailok;
            #pragma unroll
            for (int i = 0; i < 4; ++i) {
                float e = valid ? __expf((acc[mt][i] - mx[i]) * inv_scale) : 0.f;
                acc[mt][i] = e;
                sum[i] += e;
            }
        }
        float fct[4];
        #pragma unroll
        for (int i = 0; i < 4; ++i) fct[i] = qwr[i] / red16_sum(sum[i]);
        #pragma unroll
        for (int mt = 0; mt < MT_; ++mt)
            aggl[mt] += acc[mt][0] * fct[0] + acc[mt][1] * fct[1]
                      + acc[mt][2] * fct[2] + acc[mt][3] * fct[3];
    }
    #pragma unroll
    for (int mt = 0; mt < MT_; ++mt) {
        aggl[mt] += __shfl_xor(aggl[mt], 16);
        aggl[mt] += __shfl_xor(aggl[mt], 32);
    }
    if (g == 0) {
        #pragma unroll
        for (int mt = 0; mt < MT_; ++mt) aggp[w][mt * 16 + r16] = aggl[mt];
    }
    __syncthreads();
    if (t < MT_ * 16) {
        float v = 0.f;
        #pragma unroll
        for (int j = 0; j < 8; ++j) v += aggp[j][t];
        aggp[0][t] = v;
    }
    __syncthreads();
    if (w == 0) {
        float v0 = aggp[0][lane], v1 = aggp[0][lane + 64], v2 = aggp[0][lane + 128];
        const bool has3 = lane < (H_ - 192);
        float v3 = has3 ? aggp[0][lane + 192] : -INFINITY;
        float mx = wave_reduce_max(fmaxf(fmaxf(v0, v1), fmaxf(v2, v3)));
        float s = __expf(v0 - mx) + __expf(v1 - mx) + __expf(v2 - mx)
                + (has3 ? __expf(v3 - mx) : 0.f);
        s = wave_reduce_sum(s);
        if (lane == 0) { red2[0] = mx; red2[1] = s; }
    }
    __syncthreads();
    if (t < H_) {
        float v = __expf(aggp[0][t] - red2[0]) / red2[1];
        aw[b * H_ + t] = v;
        out_tail[b * H_ + t] = v;
    }
}

// blendln: z = aw*y + bg; gate = sigmoid(z); o = cl*(1 + gt*(aw-1)); LN.
// One wave per row; 4 rows per 256-thread block. (At HBM roofline.)
__global__ __launch_bounds__(256) void blendln(
    const float* __restrict__ cl, const short* __restrict__ Z,
    const float* __restrict__ aw, const float* __restrict__ bg,
    const float* __restrict__ gamma, const float* __restrict__ beta,
    float* __restrict__ out)
{
    const int t = threadIdx.x;
    const int lane = t & 63, w = t >> 6;
    const int row = blockIdx.x * 4 + w;
    const float awr = aw[row];
    const long base = (long)row * D_;

    float o[10];
    float s = 0.f, sq = 0.f;
    #pragma unroll
    for (int i = 0; i < 10; ++i) {
        const int col = lane + 64 * i;
        const float y = bf2f(Z[base + col]);
        const float c = cl[base + col];
        const float z = awr * y + bg[col];
        const float gt = 1.f / (1.f + __expf(-z));
        const float ov = c * (1.f + gt * (awr - 1.f));
        o[i] = ov; s += ov; sq += ov * ov;
    }
    s  = wave_reduce_sum(s);
    sq = wave_reduce_sum(sq);
    const float mu  = s * (1.f / D_);
    const float var = sq * (1.f / D_) - mu * mu;
    const float ri  = 1.0f / sqrtf(var + 1e-5f);
    #pragma unroll
    for (int i = 0; i < 10; ++i) {
        const int col = lane + 64 * i;
        out[base + col] = (o[i] - mu) * ri * gamma[col] + beta[col];
    }
}

extern "C" void kernel_launch(void* const* d_in, const int* in_sizes, int n_in,
                              void* d_out, int out_size, void* d_ws, size_t ws_size,
                              hipStream_t stream) {
    const float* clicked_news   = (const float*)d_in[0];   // [B,H,D]
    const float* clicked_topics = (const float*)d_in[1];   // [B,H,Dt]
    const float* cand_topics    = (const float*)d_in[2];   // [B,N,Dt]
    const float* Wq = (const float*)d_in[3];
    const float* bq = (const float*)d_in[4];
    const float* Wk = (const float*)d_in[5];
    const float* bk = (const float*)d_in[6];
    // d_in[7], d_in[8] = Wv, bv: dead code w.r.t. outputs
    const float* Wg = (const float*)d_in[9];
    const float* bg = (const float*)d_in[10];
    const float* ln_gamma = (const float*)d_in[11];
    const float* ln_beta  = (const float*)d_in[12];

    float* out = (float*)d_out;
    float* ws  = (float*)d_ws;

    // ws layout: aw, weights, then Qb; Z (bf16, half-M) ALIASES Qb (Qb is
    // dead after attn2; gemm/blendln run after attn2 on the same stream).
    float* aw   = ws;                                    // B*H floats
    short* Wq_b = (short*)(aw + (long)B_ * H_);          // 163,840
    short* Wk_b = Wq_b + (long)D_ * DT_;                 // 163,840
    short* Wg_b = Wk_b + (long)D_ * DT_;                 // 409,600 row-major [col][k]
    short* Qb   = Wg_b + (long)D_ * D_;                  // 10,485,760
    short* Z    = Qb;                                    // 16,384,000 (overlaps Qb+)
    // Kb (bf16) at start of d_out: read by attn2, overwritten by blendln.
    short* Kb = (short*)d_out;
    float* out_tail = out + (long)B_ * H_ * D_;          // attn_weights_agg

    convert_w<<<128, 256, 0, stream>>>(Wq, Wq_b, D_ * DT_);
    convert_w<<<128, 256, 0, stream>>>(Wk, Wk_b, D_ * DT_);
    convert_w<<<256, 256, 0, stream>>>(Wg, Wg_b, D_ * D_);

    // Q-proj: M=16384 -> 128 row-panels x 5 col-strips = 640 blocks (÷8 ok)
    gemm_bt<<<640, 256, 0, stream>>>(cand_topics, DT_, Wq_b, DT_, bq, Qb, 8);
    // K-proj: M=51200 -> 400 x 5 = 2000 blocks (÷8 ok)
    gemm_bt<<<2000, 256, 0, stream>>>(clicked_topics, DT_, Wk_b, DT_, bk, Kb, 8);
    attn2<<<B_, 512, 0, stream>>>(Qb, Kb, aw, out_tail);

    for (int h = 0; h < 2; ++h) {
        const long off = (long)h * MH_;
        // gate GEMM half: M=25600 -> 200 x 5 = 1000 blocks (÷8 ok)
        gemm_bt<<<1000, 256, 0, stream>>>(clicked_news + off * D_, D_,
                                          Wg_b, D_, nullptr, Z, 20);
        blendln<<<MH_ / 4, 256, 0, stream>>>(
            clicked_news + off * D_, Z, aw + off, bg, ln_gamma, ln_beta,
            out + off * D_);
    }
}

// Round 16
// 275.933 us; speedup vs baseline: 1.1004x; 1.1004x over previous
//
#include <hip/hip_runtime.h>
#include <math.h>

#define B_  256
#define H_  200
#define N_  64
#define D_  640
#define DT_ 256
#define NH_ 10
#define HD_ 64
#define MT_ 13   // 13 m-tiles of 16 cover 208 >= 200
#define MH_ 25600  // M half (B_*H_/2)

typedef __attribute__((ext_vector_type(8))) short bf16x8;
typedef __attribute__((ext_vector_type(4))) float f32x4;

__device__ __forceinline__ float wave_reduce_sum(float v) {
    #pragma unroll
    for (int m = 32; m > 0; m >>= 1) v += __shfl_xor(v, m);
    return v;
}
__device__ __forceinline__ float wave_reduce_max(float v) {
    #pragma unroll
    for (int m = 32; m > 0; m >>= 1) v = fmaxf(v, __shfl_xor(v, m));
    return v;
}
__device__ __forceinline__ float red16_sum(float v) {   // reduce over lane&15 group
    #pragma unroll
    for (int m = 1; m < 16; m <<= 1) v += __shfl_xor(v, m);
    return v;
}
__device__ __forceinline__ float red16_max(float v) {
    #pragma unroll
    for (int m = 1; m < 16; m <<= 1) v = fmaxf(v, __shfl_xor(v, m));
    return v;
}
__device__ __forceinline__ short f2bf(float x) {   // RNE bf16
    unsigned u = __float_as_uint(x);
    unsigned r = (u + 0x7fffu + ((u >> 16) & 1u)) >> 16;
    return (short)r;
}
__device__ __forceinline__ float bf2f(short s) {
    return __uint_as_float(((unsigned)(unsigned short)s) << 16);
}

__device__ __forceinline__ void gload_lds16(const void* g, void* lds) {
    __builtin_amdgcn_global_load_lds(
        (const __attribute__((address_space(1))) void*)g,
        (__attribute__((address_space(3))) void*)lds, 16, 0, 0);
}

__global__ __launch_bounds__(256) void convert_w(
    const float* __restrict__ src, short* __restrict__ dst, int n)
{
    for (int i = blockIdx.x * 256 + threadIdx.x; i < n; i += gridDim.x * 256)
        dst[i] = f2bf(src[i]);
}

// gemm_bt (r14 structure — the best measured): BM=128, BN=128, BK=64,
// 256 threads = 4 waves (2x2), acc[4][4]. Single-buffered stage inside the
// chunk loop, 2 barriers/chunk. Rule-21 both-sides swizzle; bijective XCD
// remap keeps an A-panel's 5 col-strips on one XCD.
__global__ __launch_bounds__(256, 3) void gemm_bt(
    const float* __restrict__ A, int lda,
    const short* __restrict__ Wb, int ldb,
    const float* __restrict__ bias,
    short* __restrict__ Y, int nkc)
{
    __shared__ float A_f[128 * 64];     // 32 KB fp32, slot-swizzled
    __shared__ short B_lds[128 * 64];   // 16 KB bf16, slot-swizzled
    const int t = threadIdx.x;
    const int lane = t & 63, w = t >> 6;
    const int wm = w >> 1, wn = w & 1;
    const int r16 = lane & 15, g = lane >> 4;
    const int lb = (blockIdx.x & 7) * ((int)gridDim.x >> 3) + (blockIdx.x >> 3);
    const int row0 = (lb / 5) * 128;
    const int col0 = (lb % 5) * 128;

    f32x4 acc[4][4];
    #pragma unroll
    for (int ct = 0; ct < 4; ++ct)
        #pragma unroll
        for (int rt = 0; rt < 4; ++rt) acc[ct][rt] = (f32x4){0.f,0.f,0.f,0.f};

    for (int k = 0; k < nkc; ++k) {
        const int k0 = k * 64;
        // stage A: slot u=(row, j) holds SOURCE granule (j ^ (row&7))
        #pragma unroll
        for (int j = 0; j < 8; ++j) {
            const int u = t + j * 256;
            const int row = u >> 4, jj = u & 15;
            gload_lds16(A + (long)(row0 + row) * lda + k0 + ((jj ^ (row & 7)) << 2),
                        (char*)A_f + u * 16);
        }
        // stage B: slot u=(col, j) holds SOURCE granule (j ^ (col&7))
        #pragma unroll
        for (int j = 0; j < 4; ++j) {
            const int u = t + j * 256;
            const int col = u >> 3, jj = u & 7;
            gload_lds16(Wb + (long)(col0 + col) * ldb + k0 + ((jj ^ (col & 7)) << 3),
                        (char*)B_lds + u * 16);
        }
        __syncthreads();

        #pragma unroll
        for (int kk = 0; kk < 2; ++kk) {
            bf16x8 a[4];
            #pragma unroll
            for (int rt = 0; rt < 4; ++rt) {
                const int row = wm * 64 + rt * 16 + r16;
                const int s = kk * 8 + g * 2;      // source granule (4 floats)
                float4 f0 = *(const float4*)(A_f + row * 64 + ((s ^ (row & 7)) << 2));
                float4 f1 = *(const float4*)(A_f + row * 64 + (((s + 1) ^ (row & 7)) << 2));
                bf16x8 av;
                av[0] = f2bf(f0.x); av[1] = f2bf(f0.y); av[2] = f2bf(f0.z); av[3] = f2bf(f0.w);
                av[4] = f2bf(f1.x); av[5] = f2bf(f1.y); av[6] = f2bf(f1.z); av[7] = f2bf(f1.w);
                a[rt] = av;
            }
            bf16x8 b[4];
            #pragma unroll
            for (int ct = 0; ct < 4; ++ct) {
                const int col = wn * 64 + ct * 16 + r16;
                const int sb = kk * 4 + g;         // source granule (8 shorts)
                b[ct] = *(const bf16x8*)(B_lds + col * 64 + ((sb ^ (col & 7)) << 3));
            }
            #pragma unroll
            for (int ct = 0; ct < 4; ++ct)
                #pragma unroll
                for (int rt = 0; rt < 4; ++rt)
                    acc[ct][rt] = __builtin_amdgcn_mfma_f32_16x16x32_bf16(
                                      a[rt], b[ct], acc[ct][rt], 0, 0, 0);
        }
        __syncthreads();
    }

    // write Y bf16: C/D layout col = lane&15, row = g*4 + i
    #pragma unroll
    for (int ct = 0; ct < 4; ++ct) {
        const int col = col0 + wn * 64 + ct * 16 + r16;
        const float bv = bias ? bias[col] : 0.f;
        #pragma unroll
        for (int rt = 0; rt < 4; ++rt)
            #pragma unroll
            for (int i = 0; i < 4; ++i)
                Y[(long)(row0 + wm * 64 + rt * 16 + g * 4 + i) * D_ + col] =
                    f2bf(acc[ct][rt][i] + bv);
    }
}

// attn2 v3: K head-slices staged in LDS (coalesced global_load_lds with
// rule-21 swizzle), double-buffered per half-block; STAGE(h+1) issued
// before compute(h), one barrier per head. Replaces 130 uncoalesced
// 64-line global loads per wave with 26 conflict-free ds_read_b128.
__global__ __launch_bounds__(512, 2) void attn2(
    const short* __restrict__ Qb, const short* __restrict__ Kb,
    float* __restrict__ aw, float* __restrict__ out_tail)
{
    __shared__ short K_l[2][2][208 * 64];   // [half][dbuf] 4 x 26.6 KB
    __shared__ float qn_l[N_];
    __shared__ float qw_l[N_];
    __shared__ float aggp[8][MT_ * 16];
    __shared__ float red2[2];
    const int t = threadIdx.x;
    const int lane = t & 63, w = t >> 6;
    const int wm = w & 3, hh = w >> 2;
    const int r16 = lane & 15, g = lane >> 4;
    const int b = blockIdx.x;
    const int tt = t & 255;
    const int half = t >> 8;   // == hh

    // stage K-slice of head (half*5 + hi) into K_l[half][bi].
    // slot u = row*8 + jg holds SOURCE granule (jg ^ (row&7)) of 8 bf16.
    auto STAGE_K = [&](int bi, int hi) {
        const int h = half * 5 + hi;
        #pragma unroll
        for (int j = 0; j < 7; ++j) {
            const int u = tt + j * 256;
            if (u < 208 * 8) {
                const int row = u >> 3, jg = u & 7;
                gload_lds16(Kb + ((long)(b * H_) + row) * D_ + h * HD_ +
                                ((jg ^ (row & 7)) << 3),
                            (char*)K_l[half][bi] + u * 16);
            }
        }
    };

    STAGE_K(0, 0);   // drained by the qn/qw barriers below

    // --- query-norm softmax weights qw[n] ---
    if (hh == 0) {
        const short* qrow = Qb + ((long)(b * N_ + wm * 16 + r16)) * D_ + g * 160;
        float ss = 0.f;
        #pragma unroll
        for (int j = 0; j < 20; ++j) {
            bf16x8 v = *(const bf16x8*)(qrow + j * 8);
            #pragma unroll
            for (int e = 0; e < 8; ++e) { float f = bf2f(v[e]); ss += f * f; }
        }
        ss += __shfl_xor(ss, 16);
        ss += __shfl_xor(ss, 32);
        if (g == 0) qn_l[wm * 16 + r16] = ss;
    }
    __syncthreads();
    if (w == 0) {
        float v = sqrtf(qn_l[lane]);
        float mx = wave_reduce_max(v);
        float e = __expf(v - mx);
        float s = wave_reduce_sum(e);
        qw_l[lane] = e / s;
    }
    __syncthreads();

    float qwr[4];
    #pragma unroll
    for (int i = 0; i < 4; ++i) qwr[i] = qw_l[wm * 16 + g * 4 + i];

    const float inv_scale = 0.0395284707521047f;   // 1/sqrt(640)
    float aggl[MT_];
    #pragma unroll
    for (int mt = 0; mt < MT_; ++mt) aggl[mt] = 0.f;

    for (int hi = 0; hi < 5; ++hi) {
        const int h = hh * 5 + hi;
        if (hi + 1 < 5) STAGE_K((hi + 1) & 1, hi + 1);   // issue before compute

        const short* kl = K_l[hh][hi & 1];
        const short* qbase = Qb + ((long)(b * N_ + wm * 16 + r16)) * D_ + h * HD_ + g * 8;
        bf16x8 a0 = *(const bf16x8*)(qbase);
        bf16x8 a1 = *(const bf16x8*)(qbase + 32);
        // K fragments from LDS (swizzled slots, 2-way max conflict)
        bf16x8 kb0[MT_], kb1[MT_];
        #pragma unroll
        for (int mt = 0; mt < MT_; ++mt) {
            const int row = mt * 16 + r16;
            const int s0 = g ^ (row & 7);
            const int s1 = (g + 4) ^ (row & 7);
            kb0[mt] = *(const bf16x8*)(kl + row * 64 + s0 * 8);
            kb1[mt] = *(const bf16x8*)(kl + row * 64 + s1 * 8);
        }
        f32x4 acc[MT_];
        #pragma unroll
        for (int mt = 0; mt < MT_; ++mt) {
            f32x4 z = {0.f,0.f,0.f,0.f};
            z = __builtin_amdgcn_mfma_f32_16x16x32_bf16(a0, kb0[mt], z, 0, 0, 0);
            z = __builtin_amdgcn_mfma_f32_16x16x32_bf16(a1, kb1[mt], z, 0, 0, 0);
            acc[mt] = z;
        }
        // softmax over m for rows n = wm*16 + g*4 + i (lane holds m = mt*16+r16)
        const bool tailok = (r16 < 8);   // mt==12 valid only for m<200
        float mx[4] = {-INFINITY, -INFINITY, -INFINITY, -INFINITY};
        #pragma unroll
        for (int mt = 0; mt < MT_; ++mt) {
            const bool valid = (mt < 12) || tailok;
            #pragma unroll
            for (int i = 0; i < 4; ++i)
                if (valid) mx[i] = fmaxf(mx[i], acc[mt][i]);
        }
        #pragma unroll
        for (int i = 0; i < 4; ++i) mx[i] = red16_max(mx[i]);
        float sum[4] = {0.f, 0.f, 0.f, 0.f};
        #pragma unroll
        for (int mt = 0; mt < MT_; ++mt) {
            const bool valid = (mt < 12) || tailok;
            #pragma unroll
            for (int i = 0; i < 4; ++i) {
                float e = valid ? __expf((acc[mt][i] - mx[i]) * inv_scale) : 0.f;
                acc[mt][i] = e;
                sum[i] += e;
            }
        }
        float fct[4];
        #pragma unroll
        for (int i = 0; i < 4; ++i) fct[i] = qwr[i] / red16_sum(sum[i]);
        #pragma unroll
        for (int mt = 0; mt < MT_; ++mt)
            aggl[mt] += acc[mt][0] * fct[0] + acc[mt][1] * fct[1]
                      + acc[mt][2] * fct[2] + acc[mt][3] * fct[3];

        __syncthreads();   // drains STAGE(hi+1); frees buf[hi&1] for hi+2
    }

    // reduce over g (row groups) -> wave partial agg for m = mt*16 + r16
    #pragma unroll
    for (int mt = 0; mt < MT_; ++mt) {
        aggl[mt] += __shfl_xor(aggl[mt], 16);
        aggl[mt] += __shfl_xor(aggl[mt], 32);
    }
    if (g == 0) {
        #pragma unroll
        for (int mt = 0; mt < MT_; ++mt) aggp[w][mt * 16 + r16] = aggl[mt];
    }
    __syncthreads();
    if (t < MT_ * 16) {
        float v = 0.f;
        #pragma unroll
        for (int j = 0; j < 8; ++j) v += aggp[j][t];
        aggp[0][t] = v;
    }
    __syncthreads();
    if (w == 0) {
        float v0 = aggp[0][lane], v1 = aggp[0][lane + 64], v2 = aggp[0][lane + 128];
        const bool has3 = lane < (H_ - 192);
        float v3 = has3 ? aggp[0][lane + 192] : -INFINITY;
        float mx = wave_reduce_max(fmaxf(fmaxf(v0, v1), fmaxf(v2, v3)));
        float s = __expf(v0 - mx) + __expf(v1 - mx) + __expf(v2 - mx)
                + (has3 ? __expf(v3 - mx) : 0.f);
        s = wave_reduce_sum(s);
        if (lane == 0) { red2[0] = mx; red2[1] = s; }
    }
    __syncthreads();
    if (t < H_) {
        float v = __expf(aggp[0][t] - red2[0]) / red2[1];
        aw[b * H_ + t] = v;
        out_tail[b * H_ + t] = v;
    }
}

// blendln: z = aw*y + bg; gate = sigmoid(z); o = cl*(1 + gt*(aw-1)); LN.
// One wave per row; 4 rows per 256-thread block. (At HBM roofline.)
__global__ __launch_bounds__(256) void blendln(
    const float* __restrict__ cl, const short* __restrict__ Z,
    const float* __restrict__ aw, const float* __restrict__ bg,
    const float* __restrict__ gamma, const float* __restrict__ beta,
    float* __restrict__ out)
{
    const int t = threadIdx.x;
    const int lane = t & 63, w = t >> 6;
    const int row = blockIdx.x * 4 + w;
    const float awr = aw[row];
    const long base = (long)row * D_;

    float o[10];
    float s = 0.f, sq = 0.f;
    #pragma unroll
    for (int i = 0; i < 10; ++i) {
        const int col = lane + 64 * i;
        const float y = bf2f(Z[base + col]);
        const float c = cl[base + col];
        const float z = awr * y + bg[col];
        const float gt = 1.f / (1.f + __expf(-z));
        const float ov = c * (1.f + gt * (awr - 1.f));
        o[i] = ov; s += ov; sq += ov * ov;
    }
    s  = wave_reduce_sum(s);
    sq = wave_reduce_sum(sq);
    const float mu  = s * (1.f / D_);
    const float var = sq * (1.f / D_) - mu * mu;
    const float ri  = 1.0f / sqrtf(var + 1e-5f);
    #pragma unroll
    for (int i = 0; i < 10; ++i) {
        const int col = lane + 64 * i;
        out[base + col] = (o[i] - mu) * ri * gamma[col] + beta[col];
    }
}

extern "C" void kernel_launch(void* const* d_in, const int* in_sizes, int n_in,
                              void* d_out, int out_size, void* d_ws, size_t ws_size,
                              hipStream_t stream) {
    const float* clicked_news   = (const float*)d_in[0];   // [B,H,D]
    const float* clicked_topics = (const float*)d_in[1];   // [B,H,Dt]
    const float* cand_topics    = (const float*)d_in[2];   // [B,N,Dt]
    const float* Wq = (const float*)d_in[3];
    const float* bq = (const float*)d_in[4];
    const float* Wk = (const float*)d_in[5];
    const float* bk = (const float*)d_in[6];
    // d_in[7], d_in[8] = Wv, bv: dead code w.r.t. outputs
    const float* Wg = (const float*)d_in[9];
    const float* bg = (const float*)d_in[10];
    const float* ln_gamma = (const float*)d_in[11];
    const float* ln_beta  = (const float*)d_in[12];

    float* out = (float*)d_out;
    float* ws  = (float*)d_ws;

    // ws layout: aw, weights, then Qb; Z (bf16, half-M) ALIASES Qb (Qb is
    // dead after attn2; gemm/blendln run after attn2 on the same stream).
    float* aw   = ws;                                    // B*H floats
    short* Wq_b = (short*)(aw + (long)B_ * H_);          // 163,840
    short* Wk_b = Wq_b + (long)D_ * DT_;                 // 163,840
    short* Wg_b = Wk_b + (long)D_ * DT_;                 // 409,600 row-major [col][k]
    short* Qb   = Wg_b + (long)D_ * D_;                  // 10,485,760
    short* Z    = Qb;                                    // 16,384,000 (overlaps Qb+)
    // Kb (bf16) at start of d_out: read by attn2 (incl. 8 pad rows),
    // overwritten by blendln's output afterwards.
    short* Kb = (short*)d_out;
    float* out_tail = out + (long)B_ * H_ * D_;          // attn_weights_agg

    convert_w<<<128, 256, 0, stream>>>(Wq, Wq_b, D_ * DT_);
    convert_w<<<128, 256, 0, stream>>>(Wk, Wk_b, D_ * DT_);
    convert_w<<<256, 256, 0, stream>>>(Wg, Wg_b, D_ * D_);

    // Q-proj: M=16384 -> 128 row-panels x 5 col-strips = 640 blocks (÷8 ok)
    gemm_bt<<<640, 256, 0, stream>>>(cand_topics, DT_, Wq_b, DT_, bq, Qb, 4);
    // K-proj: M=51200 -> 400 x 5 = 2000 blocks (÷8 ok)
    gemm_bt<<<2000, 256, 0, stream>>>(clicked_topics, DT_, Wk_b, DT_, bk, Kb, 4);
    attn2<<<B_, 512, 0, stream>>>(Qb, Kb, aw, out_tail);

    for (int h = 0; h < 2; ++h) {
        const long off = (long)h * MH_;
        // gate GEMM half: M=25600 -> 200 x 5 = 1000 blocks (÷8 ok)
        gemm_bt<<<1000, 256, 0, stream>>>(clicked_news + off * D_, D_,
                                          Wg_b, D_, nullptr, Z, 10);
        blendln<<<MH_ / 4, 256, 0, stream>>>(
            clicked_news + off * D_, Z, aw + off, bg, ln_gamma, ln_beta,
            out + off * D_);
    }
}

// Round 17
// 273.855 us; speedup vs baseline: 1.1088x; 1.0076x over previous
//
#include <hip/hip_runtime.h>
#include <math.h>

#define B_  256
#define H_  200
#define N_  64
#define D_  640
#define DT_ 256
#define NH_ 10
#define HD_ 64
#define MT_ 13   // 13 m-tiles of 16 cover 208 >= 200
#define MH_ 25600  // M half (B_*H_/2)

typedef __attribute__((ext_vector_type(8))) short bf16x8;
typedef __attribute__((ext_vector_type(4))) float f32x4;

__device__ __forceinline__ float wave_reduce_sum(float v) {
    #pragma unroll
    for (int m = 32; m > 0; m >>= 1) v += __shfl_xor(v, m);
    return v;
}
__device__ __forceinline__ float wave_reduce_max(float v) {
    #pragma unroll
    for (int m = 32; m > 0; m >>= 1) v = fmaxf(v, __shfl_xor(v, m));
    return v;
}
__device__ __forceinline__ float red16_sum(float v) {   // reduce over lane&15 group
    #pragma unroll
    for (int m = 1; m < 16; m <<= 1) v += __shfl_xor(v, m);
    return v;
}
__device__ __forceinline__ float red16_max(float v) {
    #pragma unroll
    for (int m = 1; m < 16; m <<= 1) v = fmaxf(v, __shfl_xor(v, m));
    return v;
}
__device__ __forceinline__ short f2bf(float x) {   // RNE bf16
    unsigned u = __float_as_uint(x);
    unsigned r = (u + 0x7fffu + ((u >> 16) & 1u)) >> 16;
    return (short)r;
}
__device__ __forceinline__ float bf2f(short s) {
    return __uint_as_float(((unsigned)(unsigned short)s) << 16);
}

__device__ __forceinline__ void gload_lds16(const void* g, void* lds) {
    __builtin_amdgcn_global_load_lds(
        (const __attribute__((address_space(1))) void*)g,
        (__attribute__((address_space(3))) void*)lds, 16, 0, 0);
}

__global__ __launch_bounds__(256) void convert_w(
    const float* __restrict__ src, short* __restrict__ dst, int n)
{
    for (int i = blockIdx.x * 256 + threadIdx.x; i < n; i += gridDim.x * 256)
        dst[i] = f2bf(src[i]);
}

// gemm_bt v3: BM=64, BN=128, BK=64, 256 threads = 4 waves (2 row-halves x
// 2 col-halves), acc[4][2]. LDS 32 KB -> 5 blocks/CU (launch_bounds(256,5)):
// five independent barrier-groups per CU overlap each other's stage drains.
// Rule-21 both-sides swizzle; bijective XCD remap keeps an A-panel's 5
// col-strips on one XCD (panel + W from that XCD's L2).
__global__ __launch_bounds__(256, 5) void gemm_bt(
    const float* __restrict__ A, int lda,
    const short* __restrict__ Wb, int ldb,
    const float* __restrict__ bias,
    short* __restrict__ Y, int nkc)
{
    __shared__ float A_f[64 * 64];      // 16 KB fp32, slot-swizzled
    __shared__ short B_lds[128 * 64];   // 16 KB bf16, slot-swizzled
    const int t = threadIdx.x;
    const int lane = t & 63, w = t >> 6;
    const int wm = w >> 1, wn = w & 1;
    const int r16 = lane & 15, g = lane >> 4;
    const int lb = (blockIdx.x & 7) * ((int)gridDim.x >> 3) + (blockIdx.x >> 3);
    const int row0 = (lb / 5) * 64;
    const int col0 = (lb % 5) * 128;

    f32x4 acc[4][2];
    #pragma unroll
    for (int ct = 0; ct < 4; ++ct) {
        acc[ct][0] = (f32x4){0.f,0.f,0.f,0.f};
        acc[ct][1] = (f32x4){0.f,0.f,0.f,0.f};
    }

    for (int k = 0; k < nkc; ++k) {
        const int k0 = k * 64;
        // stage A: 1024 granules (16B = 4 floats), 4/thread;
        // slot u=(row, jj) holds SOURCE granule (jj ^ (row&7))
        #pragma unroll
        for (int j = 0; j < 4; ++j) {
            const int u = t + j * 256;
            const int row = u >> 4, jj = u & 15;
            gload_lds16(A + (long)(row0 + row) * lda + k0 + ((jj ^ (row & 7)) << 2),
                        (char*)A_f + u * 16);
        }
        // stage B: 1024 granules (16B = 8 bf16), 4/thread;
        // slot u=(col, jj) holds SOURCE granule (jj ^ (col&7))
        #pragma unroll
        for (int j = 0; j < 4; ++j) {
            const int u = t + j * 256;
            const int col = u >> 3, jj = u & 7;
            gload_lds16(Wb + (long)(col0 + col) * ldb + k0 + ((jj ^ (col & 7)) << 3),
                        (char*)B_lds + u * 16);
        }
        __syncthreads();

        #pragma unroll
        for (int kk = 0; kk < 2; ++kk) {
            bf16x8 a[2];
            #pragma unroll
            for (int rt = 0; rt < 2; ++rt) {
                const int row = wm * 32 + rt * 16 + r16;
                const int s = kk * 8 + g * 2;      // source granule (4 floats)
                float4 f0 = *(const float4*)(A_f + row * 64 + ((s ^ (row & 7)) << 2));
                float4 f1 = *(const float4*)(A_f + row * 64 + (((s + 1) ^ (row & 7)) << 2));
                bf16x8 av;
                av[0] = f2bf(f0.x); av[1] = f2bf(f0.y); av[2] = f2bf(f0.z); av[3] = f2bf(f0.w);
                av[4] = f2bf(f1.x); av[5] = f2bf(f1.y); av[6] = f2bf(f1.z); av[7] = f2bf(f1.w);
                a[rt] = av;
            }
            #pragma unroll
            for (int ct = 0; ct < 4; ++ct) {
                const int col = wn * 64 + ct * 16 + r16;
                const int sb = kk * 4 + g;         // source granule (8 shorts)
                bf16x8 b = *(const bf16x8*)(B_lds + col * 64 + ((sb ^ (col & 7)) << 3));
                acc[ct][0] = __builtin_amdgcn_mfma_f32_16x16x32_bf16(a[0], b, acc[ct][0], 0, 0, 0);
                acc[ct][1] = __builtin_amdgcn_mfma_f32_16x16x32_bf16(a[1], b, acc[ct][1], 0, 0, 0);
            }
        }
        __syncthreads();
    }

    // write Y bf16: C/D layout col = lane&15, row = g*4 + i
    #pragma unroll
    for (int ct = 0; ct < 4; ++ct) {
        const int col = col0 + wn * 64 + ct * 16 + r16;
        const float bv = bias ? bias[col] : 0.f;
        #pragma unroll
        for (int rt = 0; rt < 2; ++rt)
            #pragma unroll
            for (int i = 0; i < 4; ++i)
                Y[(long)(row0 + wm * 32 + rt * 16 + g * 4 + i) * D_ + col] =
                    f2bf(acc[ct][rt][i] + bv);
    }
}

// attn2 v3: K head-slices staged in LDS (coalesced global_load_lds with
// rule-21 swizzle), double-buffered per half-block; STAGE(h+1) issued
// before compute(h), one barrier per head.
__global__ __launch_bounds__(512, 2) void attn2(
    const short* __restrict__ Qb, const short* __restrict__ Kb,
    float* __restrict__ aw, float* __restrict__ out_tail)
{
    __shared__ short K_l[2][2][208 * 64];   // [half][dbuf] 4 x 26.6 KB
    __shared__ float qn_l[N_];
    __shared__ float qw_l[N_];
    __shared__ float aggp[8][MT_ * 16];
    __shared__ float red2[2];
    const int t = threadIdx.x;
    const int lane = t & 63, w = t >> 6;
    const int wm = w & 3, hh = w >> 2;
    const int r16 = lane & 15, g = lane >> 4;
    const int b = blockIdx.x;
    const int tt = t & 255;
    const int half = t >> 8;   // == hh

    auto STAGE_K = [&](int bi, int hi) {
        const int h = half * 5 + hi;
        #pragma unroll
        for (int j = 0; j < 7; ++j) {
            const int u = tt + j * 256;
            if (u < 208 * 8) {
                const int row = u >> 3, jg = u & 7;
                gload_lds16(Kb + ((long)(b * H_) + row) * D_ + h * HD_ +
                                ((jg ^ (row & 7)) << 3),
                            (char*)K_l[half][bi] + u * 16);
            }
        }
    };

    STAGE_K(0, 0);   // drained by the qn/qw barriers below

    // --- query-norm softmax weights qw[n] ---
    if (hh == 0) {
        const short* qrow = Qb + ((long)(b * N_ + wm * 16 + r16)) * D_ + g * 160;
        float ss = 0.f;
        #pragma unroll
        for (int j = 0; j < 20; ++j) {
            bf16x8 v = *(const bf16x8*)(qrow + j * 8);
            #pragma unroll
            for (int e = 0; e < 8; ++e) { float f = bf2f(v[e]); ss += f * f; }
        }
        ss += __shfl_xor(ss, 16);
        ss += __shfl_xor(ss, 32);
        if (g == 0) qn_l[wm * 16 + r16] = ss;
    }
    __syncthreads();
    if (w == 0) {
        float v = sqrtf(qn_l[lane]);
        float mx = wave_reduce_max(v);
        float e = __expf(v - mx);
        float s = wave_reduce_sum(e);
        qw_l[lane] = e / s;
    }
    __syncthreads();

    float qwr[4];
    #pragma unroll
    for (int i = 0; i < 4; ++i) qwr[i] = qw_l[wm * 16 + g * 4 + i];

    const float inv_scale = 0.0395284707521047f;   // 1/sqrt(640)
    float aggl[MT_];
    #pragma unroll
    for (int mt = 0; mt < MT_; ++mt) aggl[mt] = 0.f;

    for (int hi = 0; hi < 5; ++hi) {
        const int h = hh * 5 + hi;
        if (hi + 1 < 5) STAGE_K((hi + 1) & 1, hi + 1);   // issue before compute

        const short* kl = K_l[hh][hi & 1];
        const short* qbase = Qb + ((long)(b * N_ + wm * 16 + r16)) * D_ + h * HD_ + g * 8;
        bf16x8 a0 = *(const bf16x8*)(qbase);
        bf16x8 a1 = *(const bf16x8*)(qbase + 32);
        bf16x8 kb0[MT_], kb1[MT_];
        #pragma unroll
        for (int mt = 0; mt < MT_; ++mt) {
            const int row = mt * 16 + r16;
            const int s0 = g ^ (row & 7);
            const int s1 = (g + 4) ^ (row & 7);
            kb0[mt] = *(const bf16x8*)(kl + row * 64 + s0 * 8);
            kb1[mt] = *(const bf16x8*)(kl + row * 64 + s1 * 8);
        }
        f32x4 acc[MT_];
        #pragma unroll
        for (int mt = 0; mt < MT_; ++mt) {
            f32x4 z = {0.f,0.f,0.f,0.f};
            z = __builtin_amdgcn_mfma_f32_16x16x32_bf16(a0, kb0[mt], z, 0, 0, 0);
            z = __builtin_amdgcn_mfma_f32_16x16x32_bf16(a1, kb1[mt], z, 0, 0, 0);
            acc[mt] = z;
        }
        const bool tailok = (r16 < 8);   // mt==12 valid only for m<200
        float mx[4] = {-INFINITY, -INFINITY, -INFINITY, -INFINITY};
        #pragma unroll
        for (int mt = 0; mt < MT_; ++mt) {
            const bool valid = (mt < 12) || tailok;
            #pragma unroll
            for (int i = 0; i < 4; ++i)
                if (valid) mx[i] = fmaxf(mx[i], acc[mt][i]);
        }
        #pragma unroll
        for (int i = 0; i < 4; ++i) mx[i] = red16_max(mx[i]);
        float sum[4] = {0.f, 0.f, 0.f, 0.f};
        #pragma unroll
        for (int mt = 0; mt < MT_; ++mt) {
            const bool valid = (mt < 12) || tailok;
            #pragma unroll
            for (int i = 0; i < 4; ++i) {
                float e = valid ? __expf((acc[mt][i] - mx[i]) * inv_scale) : 0.f;
                acc[mt][i] = e;
                sum[i] += e;
            }
        }
        float fct[4];
        #pragma unroll
        for (int i = 0; i < 4; ++i) fct[i] = qwr[i] / red16_sum(sum[i]);
        #pragma unroll
        for (int mt = 0; mt < MT_; ++mt)
            aggl[mt] += acc[mt][0] * fct[0] + acc[mt][1] * fct[1]
                      + acc[mt][2] * fct[2] + acc[mt][3] * fct[3];

        __syncthreads();   // drains STAGE(hi+1); frees buf[hi&1] for hi+2
    }

    #pragma unroll
    for (int mt = 0; mt < MT_; ++mt) {
        aggl[mt] += __shfl_xor(aggl[mt], 16);
        aggl[mt] += __shfl_xor(aggl[mt], 32);
    }
    if (g == 0) {
        #pragma unroll
        for (int mt = 0; mt < MT_; ++mt) aggp[w][mt * 16 + r16] = aggl[mt];
    }
    __syncthreads();
    if (t < MT_ * 16) {
        float v = 0.f;
        #pragma unroll
        for (int j = 0; j < 8; ++j) v += aggp[j][t];
        aggp[0][t] = v;
    }
    __syncthreads();
    if (w == 0) {
        float v0 = aggp[0][lane], v1 = aggp[0][lane + 64], v2 = aggp[0][lane + 128];
        const bool has3 = lane < (H_ - 192);
        float v3 = has3 ? aggp[0][lane + 192] : -INFINITY;
        float mx = wave_reduce_max(fmaxf(fmaxf(v0, v1), fmaxf(v2, v3)));
        float s = __expf(v0 - mx) + __expf(v1 - mx) + __expf(v2 - mx)
                + (has3 ? __expf(v3 - mx) : 0.f);
        s = wave_reduce_sum(s);
        if (lane == 0) { red2[0] = mx; red2[1] = s; }
    }
    __syncthreads();
    if (t < H_) {
        float v = __expf(aggp[0][t] - red2[0]) / red2[1];
        aw[b * H_ + t] = v;
        out_tail[b * H_ + t] = v;
    }
}

// blendln: z = aw*y + bg; gate = sigmoid(z); o = cl*(1 + gt*(aw-1)); LN.
// One wave per row; 4 rows per 256-thread block. (At HBM roofline.)
__global__ __launch_bounds__(256) void blendln(
    const float* __restrict__ cl, const short* __restrict__ Z,
    const float* __restrict__ aw, const float* __restrict__ bg,
    const float* __restrict__ gamma, const float* __restrict__ beta,
    float* __restrict__ out)
{
    const int t = threadIdx.x;
    const int lane = t & 63, w = t >> 6;
    const int row = blockIdx.x * 4 + w;
    const float awr = aw[row];
    const long base = (long)row * D_;

    float o[10];
    float s = 0.f, sq = 0.f;
    #pragma unroll
    for (int i = 0; i < 10; ++i) {
        const int col = lane + 64 * i;
        const float y = bf2f(Z[base + col]);
        const float c = cl[base + col];
        const float z = awr * y + bg[col];
        const float gt = 1.f / (1.f + __expf(-z));
        const float ov = c * (1.f + gt * (awr - 1.f));
        o[i] = ov; s += ov; sq += ov * ov;
    }
    s  = wave_reduce_sum(s);
    sq = wave_reduce_sum(sq);
    const float mu  = s * (1.f / D_);
    const float var = sq * (1.f / D_) - mu * mu;
    const float ri  = 1.0f / sqrtf(var + 1e-5f);
    #pragma unroll
    for (int i = 0; i < 10; ++i) {
        const int col = lane + 64 * i;
        out[base + col] = (o[i] - mu) * ri * gamma[col] + beta[col];
    }
}

extern "C" void kernel_launch(void* const* d_in, const int* in_sizes, int n_in,
                              void* d_out, int out_size, void* d_ws, size_t ws_size,
                              hipStream_t stream) {
    const float* clicked_news   = (const float*)d_in[0];   // [B,H,D]
    const float* clicked_topics = (const float*)d_in[1];   // [B,H,Dt]
    const float* cand_topics    = (const float*)d_in[2];   // [B,N,Dt]
    const float* Wq = (const float*)d_in[3];
    const float* bq = (const float*)d_in[4];
    const float* Wk = (const float*)d_in[5];
    const float* bk = (const float*)d_in[6];
    // d_in[7], d_in[8] = Wv, bv: dead code w.r.t. outputs
    const float* Wg = (const float*)d_in[9];
    const float* bg = (const float*)d_in[10];
    const float* ln_gamma = (const float*)d_in[11];
    const float* ln_beta  = (const float*)d_in[12];

    float* out = (float*)d_out;
    float* ws  = (float*)d_ws;

    // ws layout: aw, weights, then Qb; Z (bf16, half-M) ALIASES Qb (Qb is
    // dead after attn2; gemm/blendln run after attn2 on the same stream).
    float* aw   = ws;                                    // B*H floats
    short* Wq_b = (short*)(aw + (long)B_ * H_);          // 163,840
    short* Wk_b = Wq_b + (long)D_ * DT_;                 // 163,840
    short* Wg_b = Wk_b + (long)D_ * DT_;                 // 409,600 row-major [col][k]
    short* Qb   = Wg_b + (long)D_ * D_;                  // 10,485,760
    short* Z    = Qb;                                    // 16,384,000 (overlaps Qb+)
    // Kb (bf16) at start of d_out: read by attn2 (incl. 8 pad rows),
    // overwritten by blendln's output afterwards.
    short* Kb = (short*)d_out;
    float* out_tail = out + (long)B_ * H_ * D_;          // attn_weights_agg

    convert_w<<<128, 256, 0, stream>>>(Wq, Wq_b, D_ * DT_);
    convert_w<<<128, 256, 0, stream>>>(Wk, Wk_b, D_ * DT_);
    convert_w<<<256, 256, 0, stream>>>(Wg, Wg_b, D_ * D_);

    // Q-proj: M=16384 -> 256 row-panels x 5 col-strips = 1280 blocks (÷8 ok)
    gemm_bt<<<1280, 256, 0, stream>>>(cand_topics, DT_, Wq_b, DT_, bq, Qb, 4);
    // K-proj: M=51200 -> 800 x 5 = 4000 blocks (÷8 ok)
    gemm_bt<<<4000, 256, 0, stream>>>(clicked_topics, DT_, Wk_b, DT_, bk, Kb, 4);
    attn2<<<B_, 512, 0, stream>>>(Qb, Kb, aw, out_tail);

    for (int h = 0; h < 2; ++h) {
        const long off = (long)h * MH_;
        // gate GEMM half: M=25600 -> 400 x 5 = 2000 blocks (÷8 ok)
        gemm_bt<<<2000, 256, 0, stream>>>(clicked_news + off * D_, D_,
                                          Wg_b, D_, nullptr, Z, 10);
        blendln<<<MH_ / 4, 256, 0, stream>>>(
            clicked_news + off * D_, Z, aw + off, bg, ln_gamma, ln_beta,
            out + off * D_);
    }
}